// Round 1
// baseline (470.126 us; speedup 1.0000x reference)
//
#include <hip/hip_runtime.h>

// WindowAttention fused kernel for MI355X (gfx950).
// B=4096 windows, N=49 tokens, C=256, H=8 heads, hd=32. fp32 in/out, f16 MFMA inside.
//
// One block = one window (512 threads = 8 waves). Wave w owns head w in the
// attention phase. All GEMMs use v_mfma_f32_16x16x32_f16 with the verified
// layouts: A-frag row=lane&15, k=8*(lane>>4)+j (contiguous 16B -> ds_read_b128);
// D: col=lane&15, row=4*(lane>>4)+reg.

#define NTOK 49
#define DIMC 256
#define NH   8
#define HDIM 32
#define XPAD 264   // padded row stride (halfs) for x/ao staging: 528B -> banks spread
#define SCALE_F 0.17677669529663687f

typedef _Float16 v8h __attribute__((ext_vector_type(8)));
typedef float    v4f __attribute__((ext_vector_type(4)));

__device__ __forceinline__ v8h ldsv8(const _Float16* p) { return *(const v8h*)p; }

// ---------------- prep: f16 weights + gathered bias matrix into ws ----------------
__global__ void wa_prep(const float* __restrict__ Wq, const float* __restrict__ Wk,
                        const float* __restrict__ Wv, const float* __restrict__ Wp,
                        const float* __restrict__ bias_table, const int* __restrict__ rel_idx,
                        _Float16* __restrict__ wqkv, _Float16* __restrict__ wp,
                        float* __restrict__ biasm) {
    int t = blockIdx.x * blockDim.x + threadIdx.x;
    const int NW = 768 * 256;
    const int NP = 256 * 256;
    const int NB = NH * NTOK * NTOK;
    if (t < NW) {
        int n = t >> 8, k = t & 255;
        const float* W = (n < 256) ? Wq : (n < 512 ? Wk : Wv);
        wqkv[t] = (_Float16)W[(n & 255) * 256 + k];      // wqkv[n][k] = W*[n%256][k]
    } else if (t < NW + NP) {
        int u = t - NW;
        wp[u] = (_Float16)Wp[u];
    } else if (t < NW + NP + NB) {
        int u = t - NW - NP;
        int h = u / (NTOK * NTOK);
        int r = u % (NTOK * NTOK);
        biasm[u] = bias_table[rel_idx[r] * NH + h];      // biasm[h][i][j]
    }
}

// ---------------- fused window attention ----------------
__global__ __launch_bounds__(512, 2) void wa_fused(
    const float* __restrict__ x,
    const float* __restrict__ bq, const float* __restrict__ bk,
    const float* __restrict__ bv, const float* __restrict__ bp,
    const _Float16* __restrict__ wqkv, const _Float16* __restrict__ wp,
    const float* __restrict__ biasm, float* __restrict__ out) {

    __shared__ _Float16 xs[NTOK * XPAD];          // x staging; reused as ao after attn
    __shared__ _Float16 qs[NH * NTOK * HDIM];     // q[h][tok][d]
    __shared__ _Float16 kls[NH * NTOK * HDIM];    // k[h][tok][d]
    __shared__ _Float16 vT[NH * HDIM * 64];       // v^T[h][d][tok^swz], toks>=49 zeroed
    __shared__ _Float16 Ps[NH * NTOK * 64];       // P[h][qi][kj^swz]
    // total = 25872+25088+25088+32768+50176 = 158,992 B <= 160 KiB

    const int b    = blockIdx.x;
    const int tid  = threadIdx.x;
    const int wid  = tid >> 6;      // wave 0..7
    const int lane = tid & 63;
    const int g    = lane >> 4;     // 0..3
    const int fr   = lane & 15;     // 0..15

    // ---- phase 1: stage x -> f16 LDS ----
    const float* xb = x + (size_t)b * (NTOK * DIMC);
    for (int i = tid; i < (NTOK * DIMC) / 4; i += 512) {
        float4 f = ((const float4*)xb)[i];
        int e = i * 4;
        _Float16* d = &xs[(e >> 8) * XPAD + (e & 255)];
        d[0] = (_Float16)f.x; d[1] = (_Float16)f.y;
        d[2] = (_Float16)f.z; d[3] = (_Float16)f.w;
    }
    __syncthreads();

    const v4f vzero = {0.f, 0.f, 0.f, 0.f};

    // ---- phase 2a: q,k projection (32 n-tiles, 4 per wave) ----
    {
        v4f acc[4][4];
        #pragma unroll
        for (int i = 0; i < 4; ++i)
            #pragma unroll
            for (int j = 0; j < 4; ++j) acc[i][j] = vzero;
        #pragma unroll
        for (int ks = 0; ks < 8; ++ks) {
            v8h a[4];
            #pragma unroll
            for (int mt = 0; mt < 4; ++mt) {
                int row = mt * 16 + fr; row = row > 48 ? 48 : row;   // rows>=49 clamped
                a[mt] = ldsv8(&xs[row * XPAD + ks * 32 + g * 8]);
            }
            #pragma unroll
            for (int ntl = 0; ntl < 4; ++ntl) {
                int n = (wid * 4 + ntl) * 16 + fr;                    // 0..511 (q then k)
                v8h bf = *(const v8h*)&wqkv[n * 256 + ks * 32 + g * 8];
                #pragma unroll
                for (int mt = 0; mt < 4; ++mt)
                    acc[ntl][mt] = __builtin_amdgcn_mfma_f32_16x16x32_f16(a[mt], bf, acc[ntl][mt], 0, 0, 0);
            }
        }
        #pragma unroll
        for (int ntl = 0; ntl < 4; ++ntl) {
            int n = (wid * 4 + ntl) * 16 + fr;
            float bn = (n < 256) ? bq[n] : bk[n - 256];
            int h = (n & 255) >> 5;
            int d = n & 31;
            _Float16* dst = ((n < 256) ? qs : kls) + (h * NTOK) * HDIM + d;
            #pragma unroll
            for (int mt = 0; mt < 4; ++mt)
                #pragma unroll
                for (int r = 0; r < 4; ++r) {
                    int tok = mt * 16 + g * 4 + r;
                    if (tok < NTOK) dst[tok * HDIM] = (_Float16)(acc[ntl][mt][r] + bn);
                }
        }
    }

    // ---- phase 2b: v projection, computed TRANSPOSED via swapped operands ----
    // out^T[nv][tok]: A = Wv rows (M-side = v-col dim), B = x tokens (N-side).
    {
        v4f acc[2][4];
        #pragma unroll
        for (int i = 0; i < 2; ++i)
            #pragma unroll
            for (int j = 0; j < 4; ++j) acc[i][j] = vzero;
        #pragma unroll
        for (int ks = 0; ks < 8; ++ks) {
            v8h bfr[4];
            #pragma unroll
            for (int nt2 = 0; nt2 < 4; ++nt2) {
                int tok = nt2 * 16 + fr; tok = tok > 48 ? 48 : tok;
                bfr[nt2] = ldsv8(&xs[tok * XPAD + ks * 32 + g * 8]);
            }
            #pragma unroll
            for (int vl = 0; vl < 2; ++vl) {
                int nv = 512 + (wid * 2 + vl) * 16 + fr;              // Wqkv row (v block)
                v8h af = *(const v8h*)&wqkv[nv * 256 + ks * 32 + g * 8];
                #pragma unroll
                for (int nt2 = 0; nt2 < 4; ++nt2)
                    acc[vl][nt2] = __builtin_amdgcn_mfma_f32_16x16x32_f16(af, bfr[nt2], acc[vl][nt2], 0, 0, 0);
            }
        }
        // D: col = tok = fr(+16*nt2), row = v-col = 4g+r (+16*vm)
        #pragma unroll
        for (int vl = 0; vl < 2; ++vl)
            #pragma unroll
            for (int nt2 = 0; nt2 < 4; ++nt2)
                #pragma unroll
                for (int r = 0; r < 4; ++r) {
                    int c = (wid * 2 + vl) * 16 + g * 4 + r;          // v col 0..255
                    int h = c >> 5, d = c & 31;
                    int tok = nt2 * 16 + fr;                          // 0..63
                    float val = (tok < NTOK) ? (acc[vl][nt2][r] + bv[c]) : 0.f; // zero pad: avoids 0*NaN in PV
                    vT[(h * HDIM + d) * 64 + (tok ^ ((d & 7) << 3))] = (_Float16)val;
                }
    }
    __syncthreads();

    // ---- phase 3: attention, head h = wid ----
    float rowsum[4][4];
    {
        const int h = wid;
        const _Float16* qh = &qs[h * NTOK * HDIM];
        const _Float16* kh = &kls[h * NTOK * HDIM];
        _Float16* Pw = &Ps[h * NTOK * 64];

        v8h aq[4], bk8[4];
        #pragma unroll
        for (int mt = 0; mt < 4; ++mt) {
            int r = mt * 16 + fr; r = r > 48 ? 48 : r;
            aq[mt] = ldsv8(&qh[r * HDIM + g * 8]);
        }
        #pragma unroll
        for (int nt = 0; nt < 4; ++nt) {
            int c = nt * 16 + fr; c = c > 48 ? 48 : c;
            bk8[nt] = ldsv8(&kh[c * HDIM + g * 8]);
        }
        v4f s[4][4];
        #pragma unroll
        for (int mt = 0; mt < 4; ++mt)
            #pragma unroll
            for (int nt = 0; nt < 4; ++nt)
                s[mt][nt] = __builtin_amdgcn_mfma_f32_16x16x32_f16(aq[mt], bk8[nt], vzero, 0, 0, 0);

        // scale + bias + mask, then rowwise softmax (row lives on one 16-lane group)
        const float* bh = biasm + h * NTOK * NTOK;
        #pragma unroll
        for (int mt = 0; mt < 4; ++mt) {
            #pragma unroll
            for (int r = 0; r < 4; ++r) {
                int row  = mt * 16 + g * 4 + r;
                int brow = row > 48 ? 48 : row;
                float m = -3.0e38f;
                #pragma unroll
                for (int nt = 0; nt < 4; ++nt) {
                    int col = nt * 16 + fr;
                    float val = s[mt][nt][r] * SCALE_F;
                    val = (col < NTOK) ? (val + bh[brow * NTOK + col]) : -1.0e30f;
                    s[mt][nt][r] = val;
                    m = fmaxf(m, val);
                }
                #pragma unroll
                for (int off = 1; off < 16; off <<= 1) m = fmaxf(m, __shfl_xor(m, off));
                float sum = 0.f;
                #pragma unroll
                for (int nt = 0; nt < 4; ++nt) {
                    float p = __expf(s[mt][nt][r] - m);
                    s[mt][nt][r] = p;
                    sum += p;
                }
                #pragma unroll
                for (int off = 1; off < 16; off <<= 1) sum += __shfl_xor(sum, off);
                rowsum[mt][r] = sum;
            }
        }
        // write P (XOR-swizzled cols: bank-conflict-free write and b128 read)
        #pragma unroll
        for (int mt = 0; mt < 4; ++mt)
            #pragma unroll
            for (int r = 0; r < 4; ++r) {
                int row = mt * 16 + g * 4 + r;
                if (row < NTOK) {
                    #pragma unroll
                    for (int nt = 0; nt < 4; ++nt) {
                        int col = nt * 16 + fr;
                        Pw[row * 64 + (col ^ ((row & 7) << 3))] = (_Float16)s[mt][nt][r];
                    }
                }
            }
    }
    __syncthreads();   // P visible (and safe ordering before PV reads)

    {
        const int h = wid;
        const _Float16* Pw = &Ps[h * NTOK * 64];
        v4f o[4][2];
        #pragma unroll
        for (int i = 0; i < 4; ++i) { o[i][0] = vzero; o[i][1] = vzero; }
        #pragma unroll
        for (int ks = 0; ks < 2; ++ks) {
            v8h ap[4];
            #pragma unroll
            for (int mt = 0; mt < 4; ++mt) {
                int row = mt * 16 + fr; row = row > 48 ? 48 : row;
                int ch = (ks * 4 + g) ^ (row & 7);
                ap[mt] = ldsv8(&Pw[row * 64 + ch * 8]);
            }
            #pragma unroll
            for (int ntd = 0; ntd < 2; ++ntd) {
                int d  = ntd * 16 + fr;
                int ch = (ks * 4 + g) ^ (d & 7);
                v8h bv8 = ldsv8(&vT[(h * HDIM + d) * 64 + ch * 8]);
                #pragma unroll
                for (int mt = 0; mt < 4; ++mt)
                    o[mt][ntd] = __builtin_amdgcn_mfma_f32_16x16x32_f16(ap[mt], bv8, o[mt][ntd], 0, 0, 0);
            }
        }
        // normalize by rowsum (same lane<->row mapping as S) and write ao into xs
        #pragma unroll
        for (int mt = 0; mt < 4; ++mt)
            #pragma unroll
            for (int r = 0; r < 4; ++r) {
                int tok = mt * 16 + g * 4 + r;
                if (tok < NTOK) {
                    float inv = 1.f / rowsum[mt][r];
                    #pragma unroll
                    for (int ntd = 0; ntd < 2; ++ntd) {
                        int d = ntd * 16 + fr;
                        xs[tok * XPAD + h * HDIM + d] = (_Float16)(o[mt][ntd][r] * inv);
                    }
                }
            }
    }
    __syncthreads();

    // ---- phase 4: output projection (16 n-tiles, 2 per wave) ----
    {
        v4f acc[2][4];
        #pragma unroll
        for (int i = 0; i < 2; ++i)
            #pragma unroll
            for (int j = 0; j < 4; ++j) acc[i][j] = vzero;
        #pragma unroll
        for (int ks = 0; ks < 8; ++ks) {
            v8h a[4];
            #pragma unroll
            for (int mt = 0; mt < 4; ++mt) {
                int row = mt * 16 + fr; row = row > 48 ? 48 : row;
                a[mt] = ldsv8(&xs[row * XPAD + ks * 32 + g * 8]);
            }
            #pragma unroll
            for (int ntl = 0; ntl < 2; ++ntl) {
                int n = (wid * 2 + ntl) * 16 + fr;
                v8h bf = *(const v8h*)&wp[n * 256 + ks * 32 + g * 8];
                #pragma unroll
                for (int mt = 0; mt < 4; ++mt)
                    acc[ntl][mt] = __builtin_amdgcn_mfma_f32_16x16x32_f16(a[mt], bf, acc[ntl][mt], 0, 0, 0);
            }
        }
        float* ob = out + (size_t)b * (NTOK * DIMC);
        #pragma unroll
        for (int ntl = 0; ntl < 2; ++ntl) {
            int n = (wid * 2 + ntl) * 16 + fr;
            float bpn = bp[n];
            #pragma unroll
            for (int mt = 0; mt < 4; ++mt)
                #pragma unroll
                for (int r = 0; r < 4; ++r) {
                    int tok = mt * 16 + g * 4 + r;
                    if (tok < NTOK) ob[tok * DIMC + n] = acc[ntl][mt][r] + bpn;
                }
        }
    }
}

extern "C" void kernel_launch(void* const* d_in, const int* in_sizes, int n_in,
                              void* d_out, int out_size, void* d_ws, size_t ws_size,
                              hipStream_t stream) {
    const float* x          = (const float*)d_in[0];
    const float* bias_table = (const float*)d_in[1];
    const float* Wq         = (const float*)d_in[2];
    const float* bq         = (const float*)d_in[3];
    const float* Wk         = (const float*)d_in[4];
    const float* bk         = (const float*)d_in[5];
    const float* Wv         = (const float*)d_in[6];
    const float* bv         = (const float*)d_in[7];
    const float* Wp         = (const float*)d_in[8];
    const float* bp         = (const float*)d_in[9];
    const int*   rel_idx    = (const int*)d_in[10];
    float* out = (float*)d_out;

    // ws layout: wqkv f16 [768*256] | wp f16 [256*256] | biasm f32 [8*49*49]  (~601 KB)
    _Float16* wqkv = (_Float16*)d_ws;
    _Float16* wp   = wqkv + 768 * 256;
    float*    biasm = (float*)(wp + 256 * 256);

    const int TOT = 768 * 256 + 256 * 256 + NH * NTOK * NTOK;
    wa_prep<<<(TOT + 255) / 256, 256, 0, stream>>>(Wq, Wk, Wv, Wp, bias_table, rel_idx,
                                                   wqkv, wp, biasm);
    wa_fused<<<4096, 512, 0, stream>>>(x, bq, bk, bv, bp, wqkv, wp, biasm, out);
}